// Round 7
// baseline (16.234 us; speedup 1.0000x reference)
//
#include <hip/hip_runtime.h>

// Paste2dMulti: N=64, M=8, C=3, H=W=64, canvas l=256.
// Gather form. Thread = one output column x 8-row vertical strip, with the
// R6 hybrid load scheme that won at 4 rows:
//   - wave-level skip via __any(valid): exec stays FULL inside
//   - source col clamped -> every lane issues a legal load (clamped lanes
//     alias the boundary dword, same 64B segment, ~no extra transactions)
//   - invalid lanes zeroed by one v_cndmask folded into the x-mask
//   - branch-free body -> all surviving-m loads (24/lane) overlap in flight
//   - nontemporal stores (write-once output)
// Grid 64*32 = 2048 blocks = 8192 waves = 32 waves/CU: one full pass.

__device__ __forceinline__ float clamp01(float v) {
    return fminf(fmaxf(v, 0.0f), 1.0f);   // -> v_med3_f32
}

__global__ __launch_bounds__(256) void Paste2dMulti_kernel(
    const float* __restrict__ coords,   // [64][8][4]
    const float* __restrict__ images,   // [64][8][3][64][64]
    float* __restrict__ out)            // [64][1][256][256]
{
    const int bid  = blockIdx.x;       // 64 n * 32 bands
    const int n    = bid >> 5;         // block-uniform
    const int band = bid & 31;
    const int col  = threadIdx.x;      // 0..255; each wave = 64 consecutive cols
    const int r0   = band * 8;         // rows r0 .. r0+7 (block-uniform)

    const float fc = (float)col;
    const float* cb = coords + n * 32;
    const float* ib = images + (size_t)n * (8 * 3 * 4096);

    float acc[8] = {0.f, 0.f, 0.f, 0.f, 0.f, 0.f, 0.f, 0.f};

    #pragma unroll
    for (int m = 0; m < 8; ++m) {
        const float c1  = cb[m * 4 + 1];
        const int   y0  = (int)c1;         // trunc (coords >= 0)
        const int   srl = r0 - y0;         // source row of strip row 0
        if (srl + 7 < 0 || srl >= 64) continue;   // scalar (block-uniform) skip

        const float c0 = cb[m * 4 + 0];
        const int   x0 = (int)c0;
        const int   sc = col - x0;
        const bool  valid = (unsigned)sc < 64u;
        if (!__any(valid)) continue;       // wave-uniform skip; exec full inside

        const float c2 = cb[m * 4 + 2];
        const float c3 = cb[m * 4 + 3];
        float xm = clamp01(fc - c0 + 1.f) * clamp01(c2 + 1.f - fc);
        xm = valid ? xm : 0.f;             // one v_cndmask, no divergent branch

        const int  scc = min(max(sc, 0), 63);     // always-legal source col
        const float* p = ib + m * (3 * 4096) + srl * 64 + scc;

        #pragma unroll
        for (int k = 0; k < 8; ++k) {
            const int sr = srl + k;            // block-uniform validity
            if (sr < 0 || sr >= 64) continue;  // scalar branch
            const float fr = (float)(r0 + k);
            const float ym = clamp01(fr - c1 + 1.f) * clamp01(c3 + 1.f - fr);
            const float* q = p + k * 64;
            const float s = q[0] + q[4096] + q[2 * 4096];   // 3 coalesced dwords
            acc[k] = fmaf(xm * ym, s, acc[k]);
        }
    }

    float* o = out + (size_t)n * 65536 + (size_t)r0 * 256 + col;
    #pragma unroll
    for (int k = 0; k < 8; ++k)
        __builtin_nontemporal_store(fminf(1.f, acc[k]), o + k * 256);
}

extern "C" void kernel_launch(void* const* d_in, const int* in_sizes, int n_in,
                              void* d_out, int out_size, void* d_ws, size_t ws_size,
                              hipStream_t stream) {
    const float* coords = (const float*)d_in[0];
    const float* images = (const float*)d_in[1];
    float* out = (float*)d_out;

    // 64 batches * 32 bands of 8 rows; 256 threads = one column each.
    Paste2dMulti_kernel<<<64 * 32, 256, 0, stream>>>(coords, images, out);
}

// Round 11
// 15.969 us; speedup vs baseline: 1.0166x; 1.0166x over previous
//
#include <hip/hip_runtime.h>

// Paste2dMulti: N=64, M=8, C=3, H=W=64, canvas l=256.
// R6 structure (4-row strip per thread, hybrid branch-free loads) with
// 1024-thread blocks to cut workgroup count 4x (4096 -> 1024 WGs):
// block = 16-row x 256-col band = 4 row-groups x (4 waves x 64 cols).
// Wave count unchanged (16384), occupancy unchanged (2 WGs = 32 waves/CU).
// Tests the hypothesis that the remaining ~12us over the ~2us compute
// model is WG dispatch/ramp overhead.

__device__ __forceinline__ float clamp01(float v) {
    return fminf(fmaxf(v, 0.0f), 1.0f);   // -> v_med3_f32
}

__global__ __launch_bounds__(1024) void Paste2dMulti_kernel(
    const float* __restrict__ coords,   // [64][8][4]
    const float* __restrict__ images,   // [64][8][3][64][64]
    float* __restrict__ out)            // [64][1][256][256]
{
    const int bid  = blockIdx.x;        // 64 n * 16 bands
    const int n    = bid >> 4;          // block-uniform
    const int band = bid & 15;
    const int tid  = threadIdx.x;       // 0..1023
    const int col  = tid & 255;         // wave = 64 consecutive cols
    const int rg   = tid >> 8;          // row-group 0..3 (wave-uniform)
    const int r0   = band * 16 + rg * 4;   // rows r0 .. r0+3 (wave-uniform)

    const float fc = (float)col;
    const float* cb = coords + n * 32;
    const float* ib = images + (size_t)n * (8 * 3 * 4096);

    float acc0 = 0.f, acc1 = 0.f, acc2 = 0.f, acc3 = 0.f;

    #pragma unroll
    for (int m = 0; m < 8; ++m) {
        const float c1  = cb[m * 4 + 1];
        const int   y0  = (int)c1;         // trunc (coords >= 0)
        const int   srl = r0 - y0;         // source row of strip row 0
        if (srl + 3 < 0 || srl >= 64) continue;   // wave-uniform skip

        const float c0 = cb[m * 4 + 0];
        const int   x0 = (int)c0;
        const int   sc = col - x0;
        const bool  valid = (unsigned)sc < 64u;
        if (!__any(valid)) continue;       // wave-uniform skip; exec full inside

        const float c2 = cb[m * 4 + 2];
        const float c3 = cb[m * 4 + 3];
        float xm = clamp01(fc - c0 + 1.f) * clamp01(c2 + 1.f - fc);
        xm = valid ? xm : 0.f;             // one v_cndmask, no divergent branch

        const int  scc = min(max(sc, 0), 63);     // always-legal source col
        const float* p = ib + m * (3 * 4096) + srl * 64 + scc;

        #pragma unroll
        for (int k = 0; k < 4; ++k) {
            const int sr = srl + k;            // wave-uniform validity
            if (sr < 0 || sr >= 64) continue;  // scalar branch
            const float fr = (float)(r0 + k);
            const float ym = clamp01(fr - c1 + 1.f) * clamp01(c3 + 1.f - fr);
            const float* q = p + k * 64;
            const float s = q[0] + q[4096] + q[2 * 4096];   // 3 coalesced dwords
            const float w = xm * ym;
            if (k == 0) acc0 = fmaf(w, s, acc0);
            if (k == 1) acc1 = fmaf(w, s, acc1);
            if (k == 2) acc2 = fmaf(w, s, acc2);
            if (k == 3) acc3 = fmaf(w, s, acc3);
        }
    }

    float* o = out + (size_t)n * 65536 + (size_t)r0 * 256 + col;
    __builtin_nontemporal_store(fminf(1.f, acc0), o);
    __builtin_nontemporal_store(fminf(1.f, acc1), o + 256);
    __builtin_nontemporal_store(fminf(1.f, acc2), o + 512);
    __builtin_nontemporal_store(fminf(1.f, acc3), o + 768);
}

extern "C" void kernel_launch(void* const* d_in, const int* in_sizes, int n_in,
                              void* d_out, int out_size, void* d_ws, size_t ws_size,
                              hipStream_t stream) {
    const float* coords = (const float*)d_in[0];
    const float* images = (const float*)d_in[1];
    float* out = (float*)d_out;

    // 64 batches * 16 bands of 16 rows; 1024 threads = 4 row-groups x 256 cols.
    Paste2dMulti_kernel<<<64 * 16, 1024, 0, stream>>>(coords, images, out);
}

// Round 12
// 13.720 us; speedup vs baseline: 1.1833x; 1.1639x over previous
//
#include <hip/hip_runtime.h>

// Paste2dMulti: N=64, M=8, C=3, H=W=64, canvas l=256.
// R6 WINNER restored verbatim (13.69 us, best of 8 structural variants).
// Gather form. Thread = one output column x 4-row vertical strip.
// Hybrid load scheme:
//   - wave-level skip via __any(valid): exec stays FULL inside
//   - source col clamped -> every lane issues a legal load (clamped lanes
//     alias the boundary dword, same 64B segment, ~no extra transactions)
//   - invalid lanes zeroed by one v_cndmask folded into the x-mask
//   - branch-free body -> all surviving-m loads overlap in flight
//   - nontemporal stores (write-once output)
// Refuted alternatives: 4-col/thread (R2 19.8), full clamp-all-lanes (R4
// 18.7), 8-row strips (R5 19.9 / R7 16.2), 1024-thr blocks (R11 16.0).

__device__ __forceinline__ float clamp01(float v) {
    return fminf(fmaxf(v, 0.0f), 1.0f);   // -> v_med3_f32
}

__global__ __launch_bounds__(256) void Paste2dMulti_kernel(
    const float* __restrict__ coords,   // [64][8][4]
    const float* __restrict__ images,   // [64][8][3][64][64]
    float* __restrict__ out)            // [64][1][256][256]
{
    const int bid  = blockIdx.x;       // 64 n * 64 bands
    const int n    = bid >> 6;         // block-uniform
    const int band = bid & 63;
    const int col  = threadIdx.x;      // 0..255; each wave = 64 consecutive cols
    const int r0   = band * 4;         // rows r0 .. r0+3 (block-uniform)

    const float fc = (float)col;
    const float* cb = coords + n * 32;
    const float* ib = images + (size_t)n * (8 * 3 * 4096);

    float acc0 = 0.f, acc1 = 0.f, acc2 = 0.f, acc3 = 0.f;

    #pragma unroll
    for (int m = 0; m < 8; ++m) {
        const float c1  = cb[m * 4 + 1];
        const int   y0  = (int)c1;         // trunc (coords >= 0)
        const int   srl = r0 - y0;         // source row of strip row 0
        if (srl + 3 < 0 || srl >= 64) continue;   // scalar (block-uniform) skip

        const float c0 = cb[m * 4 + 0];
        const int   x0 = (int)c0;
        const int   sc = col - x0;
        const bool  valid = (unsigned)sc < 64u;
        if (!__any(valid)) continue;       // wave-uniform skip; exec full inside

        const float c2 = cb[m * 4 + 2];
        const float c3 = cb[m * 4 + 3];
        float xm = clamp01(fc - c0 + 1.f) * clamp01(c2 + 1.f - fc);
        xm = valid ? xm : 0.f;             // one v_cndmask, no divergent branch

        const int  scc = min(max(sc, 0), 63);     // always-legal source col
        const float* p = ib + m * (3 * 4096) + srl * 64 + scc;

        #pragma unroll
        for (int k = 0; k < 4; ++k) {
            const int sr = srl + k;            // block-uniform validity
            if (sr < 0 || sr >= 64) continue;  // scalar branch
            const float fr = (float)(r0 + k);
            const float ym = clamp01(fr - c1 + 1.f) * clamp01(c3 + 1.f - fr);
            const float* q = p + k * 64;
            const float s = q[0] + q[4096] + q[2 * 4096];   // 3 coalesced dwords
            const float w = xm * ym;
            if (k == 0) acc0 = fmaf(w, s, acc0);
            if (k == 1) acc1 = fmaf(w, s, acc1);
            if (k == 2) acc2 = fmaf(w, s, acc2);
            if (k == 3) acc3 = fmaf(w, s, acc3);
        }
    }

    float* o = out + (size_t)n * 65536 + (size_t)r0 * 256 + col;
    __builtin_nontemporal_store(fminf(1.f, acc0), o);
    __builtin_nontemporal_store(fminf(1.f, acc1), o + 256);
    __builtin_nontemporal_store(fminf(1.f, acc2), o + 512);
    __builtin_nontemporal_store(fminf(1.f, acc3), o + 768);
}

extern "C" void kernel_launch(void* const* d_in, const int* in_sizes, int n_in,
                              void* d_out, int out_size, void* d_ws, size_t ws_size,
                              hipStream_t stream) {
    const float* coords = (const float*)d_in[0];
    const float* images = (const float*)d_in[1];
    float* out = (float*)d_out;

    // 64 batches * 64 bands of 4 rows; 256 threads = one column each.
    Paste2dMulti_kernel<<<64 * 64, 256, 0, stream>>>(coords, images, out);
}